// Round 6
// baseline (218.495 us; speedup 1.0000x reference)
//
#include <hip/hip_runtime.h>
#include <stdint.h>

#define K_TOP 10
#define NSAMP 500
#define DIM 256
#define BATCH 8
#define PATCHES_ELEMS (8LL * 10 * 3 * 128 * 128)  // 3,932,160

// ---------------------------------------------------------------------------
// Threefry-2x32, key = (0,1)  (jax.random.key(1) -> (0u, 1u))
// Verified against Random123 test vectors.
// ---------------------------------------------------------------------------
__device__ __forceinline__ void threefry2x32_01(uint32_t x0, uint32_t x1,
                                                uint32_t& o0, uint32_t& o1) {
    const uint32_t ks0 = 0u;
    const uint32_t ks1 = 1u;
    const uint32_t ks2 = 0u ^ 1u ^ 0x1BD11BDAu;  // 0x1BD11BDB
    x0 += ks0; x1 += ks1;
#define TF_RND(r) { x0 += x1; x1 = (x1 << (r)) | (x1 >> (32 - (r))); x1 ^= x0; }
    TF_RND(13) TF_RND(15) TF_RND(26) TF_RND(6)
    x0 += ks1; x1 += ks2 + 1u;
    TF_RND(17) TF_RND(29) TF_RND(16) TF_RND(24)
    x0 += ks2; x1 += ks0 + 2u;
    TF_RND(13) TF_RND(15) TF_RND(26) TF_RND(6)
    x0 += ks0; x1 += ks1 + 3u;
    TF_RND(17) TF_RND(29) TF_RND(16) TF_RND(24)
    x0 += ks1; x1 += ks2 + 4u;
    TF_RND(13) TF_RND(15) TF_RND(26) TF_RND(6)
    x0 += ks2; x1 += ks0 + 5u;
#undef TF_RND
    o0 = x0; o1 = x1;
}

// XLA f32 ErfInv polynomial (Giles) — matches xla math.cc ErfInv32.
__device__ __forceinline__ float erfinv_xla(float x) {
    float w = -log1pf(-x * x);
    float p;
    if (w < 5.0f) {
        w = w - 2.5f;
        p = 2.81022636e-08f;
        p = fmaf(p, w, 3.43273939e-07f);
        p = fmaf(p, w, -3.5233877e-06f);
        p = fmaf(p, w, -4.39150654e-06f);
        p = fmaf(p, w, 0.00021858087f);
        p = fmaf(p, w, -0.00125372503f);
        p = fmaf(p, w, -0.00417768164f);
        p = fmaf(p, w, 0.246640727f);
        p = fmaf(p, w, 1.50140941f);
    } else {
        w = sqrtf(w) - 3.0f;
        p = -0.000200214257f;
        p = fmaf(p, w, 0.000100950558f);
        p = fmaf(p, w, 0.00134934322f);
        p = fmaf(p, w, -0.00367342844f);
        p = fmaf(p, w, 0.00573950773f);
        p = fmaf(p, w, -0.0076224613f);
        p = fmaf(p, w, 0.00943887047f);
        p = fmaf(p, w, 1.00167406f);
        p = fmaf(p, w, 2.83297682f);
    }
    return p * x;
}

// jax_threefry_partitionable=True (default in modern JAX):
//   counts = iota(u64); bits = o0 ^ o1 of threefry(key, (counts>>32, counts&~0))
// For our sizes counts < 2^32, so counter = (0, flat) and bits = o0 ^ o1.
__device__ __forceinline__ float jax_normal_at(uint32_t flat) {
    uint32_t o0, o1;
    threefry2x32_01(0u, flat, o0, o1);
    uint32_t bits = o0 ^ o1;
    float f = __uint_as_float((bits >> 9) | 0x3f800000u) - 1.0f;  // [0,1)
    const float lo = -0.99999994f;  // nextafter(-1,0) in f32
    float u = fmaxf(lo, fmaf(f, 2.0f, lo));  // hi-lo rounds to exactly 2.0f
    return 1.4142135381698608f * erfinv_xla(u);  // float32(sqrt(2))
}

// ---------------------------------------------------------------------------
// Kernel 1: entropy + normalize + zero counts.  One block of 256 threads.
// ---------------------------------------------------------------------------
__global__ __launch_bounds__(256) void scores_kernel(
    const float* __restrict__ scores, float* __restrict__ norm,
    int* __restrict__ counts, float* __restrict__ entr_out) {
    __shared__ float sbuf[256];
    const int tid = threadIdx.x;
    for (int i = tid; i < BATCH * K_TOP * DIM; i += 256) counts[i] = 0;
    float entacc = 0.0f;
    for (int b = 0; b < BATCH; ++b) {
        float s = scores[b * DIM + tid];
        // max
        sbuf[tid] = s; __syncthreads();
        for (int st = 128; st > 0; st >>= 1) {
            if (tid < st) sbuf[tid] = fmaxf(sbuf[tid], sbuf[tid + st]);
            __syncthreads();
        }
        float mx = sbuf[0]; __syncthreads();
        // min
        sbuf[tid] = s; __syncthreads();
        for (int st = 128; st > 0; st >>= 1) {
            if (tid < st) sbuf[tid] = fminf(sbuf[tid], sbuf[tid + st]);
            __syncthreads();
        }
        float mn = sbuf[0]; __syncthreads();
        // sum(exp(s - max))
        float sh = s - mx;
        sbuf[tid] = expf(sh); __syncthreads();
        for (int st = 128; st > 0; st >>= 1) {
            if (tid < st) sbuf[tid] += sbuf[tid + st];
            __syncthreads();
        }
        float sum = sbuf[0]; __syncthreads();
        float logp = sh - logf(sum);
        float p = expf(logp);
        sbuf[tid] = p * logp; __syncthreads();
        for (int st = 128; st > 0; st >>= 1) {
            if (tid < st) sbuf[tid] += sbuf[tid + st];
            __syncthreads();
        }
        if (tid == 0) entacc -= sbuf[0];
        __syncthreads();
        norm[b * DIM + tid] = (s - mn) / (mx - mn + 1e-5f);
    }
    if (tid == 0) entr_out[0] = entacc * 0.125f;  // mean over 8 (exact /8)
}

// ---------------------------------------------------------------------------
// Kernel 2: perturbed top-k.  One wave per (b, sample) row; 4 waves/block.
// ---------------------------------------------------------------------------
__global__ __launch_bounds__(256) void topk_kernel(
    const float* __restrict__ norm, int* __restrict__ counts) {
    const int wid = threadIdx.x >> 6;
    const int lane = threadIdx.x & 63;
    const int r = blockIdx.x * 4 + wid;  // 0..3999  (= b*500 + n)
    const int b = r / NSAMP;

    const uint32_t base = (uint32_t)r * 256u;
    float v0 = norm[b * DIM + lane]       + jax_normal_at(base + (uint32_t)lane)         * 0.05f;
    float v1 = norm[b * DIM + 64 + lane]  + jax_normal_at(base + 64u + (uint32_t)lane)   * 0.05f;
    float v2 = norm[b * DIM + 128 + lane] + jax_normal_at(base + 128u + (uint32_t)lane)  * 0.05f;
    float v3 = norm[b * DIM + 192 + lane] + jax_normal_at(base + 192u + (uint32_t)lane)  * 0.05f;

    int chosen[K_TOP];
#pragma unroll
    for (int it = 0; it < K_TOP; ++it) {
        float bv = v0; int bd = lane;
        { int d = 64 + lane;  if (v1 > bv || (v1 == bv && d < bd)) { bv = v1; bd = d; } }
        { int d = 128 + lane; if (v2 > bv || (v2 == bv && d < bd)) { bv = v2; bd = d; } }
        { int d = 192 + lane; if (v3 > bv || (v3 == bv && d < bd)) { bv = v3; bd = d; } }
#pragma unroll
        for (int off = 1; off < 64; off <<= 1) {
            float ov = __shfl_xor(bv, off, 64);
            int   od = __shfl_xor(bd, off, 64);
            if (ov > bv || (ov == bv && od < bd)) { bv = ov; bd = od; }
        }
        chosen[it] = bd;
        if ((bd & 63) == lane) {
            int q = bd >> 6;
            if (q == 0) v0 = -__builtin_inff();
            else if (q == 1) v1 = -__builtin_inff();
            else if (q == 2) v2 = -__builtin_inff();
            else v3 = -__builtin_inff();
        }
    }
    // sort 10 indices ascending (identical in every lane; static network)
#pragma unroll
    for (int a = 0; a < K_TOP - 1; ++a)
#pragma unroll
        for (int t = 0; t < K_TOP - 1 - a; ++t) {
            int x0 = chosen[t], x1 = chosen[t + 1];
            chosen[t] = min(x0, x1);
            chosen[t + 1] = max(x0, x1);
        }
    if (lane == 0) {
        const int cb = b * K_TOP * DIM;
#pragma unroll
        for (int k = 0; k < K_TOP; ++k)
            atomicAdd(&counts[cb + (k << 8) + chosen[k]], 1);
    }
}

// ---------------------------------------------------------------------------
// Kernel 3: per-batch union compaction of nonzero windows + 10-wide weights.
// 8 blocks x 64 lanes.
// ---------------------------------------------------------------------------
__global__ __launch_bounds__(64) void compact_union_kernel(
    const int* __restrict__ counts, int* __restrict__ u_ij,
    float* __restrict__ u_wt, int* __restrict__ u_n) {
    const int b = blockIdx.x;
    const int lane = threadIdx.x;
    int any0 = 0, any1 = 0, any2 = 0, any3 = 0;
    const int d0 = lane * 4;
#pragma unroll
    for (int k = 0; k < K_TOP; ++k) {
        const int* cb = counts + (b * K_TOP + k) * DIM;
        any0 |= cb[d0 + 0];
        any1 |= cb[d0 + 1];
        any2 |= cb[d0 + 2];
        any3 |= cb[d0 + 3];
    }
    int n = (any0 > 0) + (any1 > 0) + (any2 > 0) + (any3 > 0);
    int incl = n;
#pragma unroll
    for (int off = 1; off < 64; off <<= 1) {
        int t = __shfl_up(incl, off, 64);
        if (lane >= off) incl += t;
    }
    int pos = b * DIM + (incl - n);
#define EMIT(ANY, DD)                                                        \
    if (ANY > 0) {                                                           \
        u_ij[pos] = (DD);                                                    \
        _Pragma("unroll")                                                    \
        for (int k = 0; k < K_TOP; ++k)                                      \
            u_wt[pos * K_TOP + k] =                                          \
                (float)counts[(b * K_TOP + k) * DIM + (DD)] / 500.0f;        \
        pos++;                                                               \
    }
    EMIT(any0, d0 + 0)
    EMIT(any1, d0 + 1)
    EMIT(any2, d0 + 2)
    EMIT(any3, d0 + 3)
#undef EMIT
    if (lane == 63) u_n[b] = incl;
}

// ---------------------------------------------------------------------------
// Kernel 4: gather/accumulate patches. Block = (b, c, 8-row chunk);
// each thread: 10 float4 accumulators (one per k) -> each x load reused 10x.
// grid = 8*3*16 = 384 blocks x 256 threads.
// ---------------------------------------------------------------------------
__global__ __launch_bounds__(256) void gather_kernel(
    const float* __restrict__ x, const int* __restrict__ u_ij,
    const float* __restrict__ u_wt, const int* __restrict__ u_n,
    float* __restrict__ out) {
    __shared__ int   s_ij[DIM];
    __shared__ float s_wt[DIM * K_TOP];

    const int blk = blockIdx.x;
    const int hc = blk & 15;        // 0..15 -> rows h = hc*8 .. hc*8+7
    const int bc = blk >> 4;        // b*3 + c
    const int c = bc % 3;
    const int b = bc / 3;
    const int nnz = u_n[b];
    const int tid = threadIdx.x;

    if (tid < nnz) s_ij[tid] = u_ij[b * DIM + tid];
    for (int i = tid; i < nnz * K_TOP; i += 256)
        s_wt[i] = u_wt[b * DIM * K_TOP + i];
    __syncthreads();

    const int h = hc * 8 + (tid >> 5);
    const int w0 = (tid & 31) << 2;
    const float* img = x + (size_t)bc * (1024 * 1024);

    float4 acc[K_TOP];
#pragma unroll
    for (int k = 0; k < K_TOP; ++k) acc[k] = make_float4(0.f, 0.f, 0.f, 0.f);

    for (int tt = 0; tt < nnz; ++tt) {
        const int ij = s_ij[tt];
        const int i = ij >> 4, j = ij & 15;
        const int y = i * 64 + h - 32;
        const int xc = j * 64 + w0 - 32;  // multiple of 4 -> quads never split
        if ((unsigned)y < 1024u && (unsigned)xc < 1024u) {
            const float4 v = *(const float4*)(img + (size_t)y * 1024 + xc);
#pragma unroll
            for (int k = 0; k < K_TOP; ++k) {
                const float wt = s_wt[tt * K_TOP + k];
                acc[k].x = fmaf(wt, v.x, acc[k].x);
                acc[k].y = fmaf(wt, v.y, acc[k].y);
                acc[k].z = fmaf(wt, v.z, acc[k].z);
                acc[k].w = fmaf(wt, v.w, acc[k].w);
            }
        }
    }
#pragma unroll
    for (int k = 0; k < K_TOP; ++k) {
        const size_t oidx =
            (((size_t)(b * K_TOP + k) * 3 + c) * 128 + h) * 128 + w0;
        *(float4*)(out + oidx) = acc[k];
    }
}

// ---------------------------------------------------------------------------
extern "C" void kernel_launch(void* const* d_in, const int* in_sizes, int n_in,
                              void* d_out, int out_size, void* d_ws,
                              size_t ws_size, hipStream_t stream) {
    const float* x_high = (const float*)d_in[0];   // (8,3,1024,1024) f32
    const float* scores = (const float*)d_in[1];   // (8,16,16) f32
    float* out = (float*)d_out;                    // 3,932,160 patches + 1 entr

    // workspace layout
    float* norm  = (float*)d_ws;                         // 2048 f
    int*   counts = (int*)(norm + BATCH * DIM);          // 20480 i
    int*   u_ij  = counts + BATCH * K_TOP * DIM;         // 2048 i
    float* u_wt  = (float*)(u_ij + BATCH * DIM);         // 20480 f
    int*   u_n   = (int*)(u_wt + BATCH * DIM * K_TOP);   // 8 i

    scores_kernel<<<1, 256, 0, stream>>>(scores, norm, counts,
                                         out + PATCHES_ELEMS);
    topk_kernel<<<1000, 256, 0, stream>>>(norm, counts);
    compact_union_kernel<<<BATCH, 64, 0, stream>>>(counts, u_ij, u_wt, u_n);
    gather_kernel<<<BATCH * 3 * 16, 256, 0, stream>>>(x_high, u_ij, u_wt, u_n,
                                                      out);
}

// Round 7
// 197.222 us; speedup vs baseline: 1.1079x; 1.1079x over previous
//
#include <hip/hip_runtime.h>
#include <stdint.h>

#define K_TOP 10
#define NSAMP 500
#define DIM 256
#define BATCH 8
#define PATCHES_ELEMS (8LL * 10 * 3 * 128 * 128)  // 3,932,160

// ---------------------------------------------------------------------------
// Threefry-2x32, key = (0,1)  (jax.random.key(1) -> (0u, 1u))
// ---------------------------------------------------------------------------
__device__ __forceinline__ void threefry2x32_01(uint32_t x0, uint32_t x1,
                                                uint32_t& o0, uint32_t& o1) {
    const uint32_t ks0 = 0u;
    const uint32_t ks1 = 1u;
    const uint32_t ks2 = 0u ^ 1u ^ 0x1BD11BDAu;  // 0x1BD11BDB
    x0 += ks0; x1 += ks1;
#define TF_RND(r) { x0 += x1; x1 = (x1 << (r)) | (x1 >> (32 - (r))); x1 ^= x0; }
    TF_RND(13) TF_RND(15) TF_RND(26) TF_RND(6)
    x0 += ks1; x1 += ks2 + 1u;
    TF_RND(17) TF_RND(29) TF_RND(16) TF_RND(24)
    x0 += ks2; x1 += ks0 + 2u;
    TF_RND(13) TF_RND(15) TF_RND(26) TF_RND(6)
    x0 += ks0; x1 += ks1 + 3u;
    TF_RND(17) TF_RND(29) TF_RND(16) TF_RND(24)
    x0 += ks1; x1 += ks2 + 4u;
    TF_RND(13) TF_RND(15) TF_RND(26) TF_RND(6)
    x0 += ks2; x1 += ks0 + 5u;
#undef TF_RND
    o0 = x0; o1 = x1;
}

// XLA f32 ErfInv polynomial (Giles).
__device__ __forceinline__ float erfinv_xla(float x) {
    float w = -log1pf(-x * x);
    float p;
    if (w < 5.0f) {
        w = w - 2.5f;
        p = 2.81022636e-08f;
        p = fmaf(p, w, 3.43273939e-07f);
        p = fmaf(p, w, -3.5233877e-06f);
        p = fmaf(p, w, -4.39150654e-06f);
        p = fmaf(p, w, 0.00021858087f);
        p = fmaf(p, w, -0.00125372503f);
        p = fmaf(p, w, -0.00417768164f);
        p = fmaf(p, w, 0.246640727f);
        p = fmaf(p, w, 1.50140941f);
    } else {
        w = sqrtf(w) - 3.0f;
        p = -0.000200214257f;
        p = fmaf(p, w, 0.000100950558f);
        p = fmaf(p, w, 0.00134934322f);
        p = fmaf(p, w, -0.00367342844f);
        p = fmaf(p, w, 0.00573950773f);
        p = fmaf(p, w, -0.0076224613f);
        p = fmaf(p, w, 0.00943887047f);
        p = fmaf(p, w, 1.00167406f);
        p = fmaf(p, w, 2.83297682f);
    }
    return p * x;
}

// jax_threefry_partitionable: bits = o0 ^ o1 of threefry(key, (0, flat)).
// VERIFIED on HW round 6: absmax 0.0078 -> exact RNG realization.
__device__ __forceinline__ float jax_normal_at(uint32_t flat) {
    uint32_t o0, o1;
    threefry2x32_01(0u, flat, o0, o1);
    uint32_t bits = o0 ^ o1;
    float f = __uint_as_float((bits >> 9) | 0x3f800000u) - 1.0f;  // [0,1)
    const float lo = -0.99999994f;  // nextafter(-1,0) in f32
    float u = fmaxf(lo, fmaf(f, 2.0f, lo));  // hi-lo rounds to exactly 2.0f
    return 1.4142135381698608f * erfinv_xla(u);  // float32(sqrt(2))
}

// ---------------------------------------------------------------------------
// Kernel 1: entropy + normalize + zero counts.  One block, wave-parallel:
// 4 waves x 2 batches each, shfl_xor reductions, single barrier.
// norm expression identical to previous (bit-exact) version.
// ---------------------------------------------------------------------------
__global__ __launch_bounds__(256) void scores_kernel(
    const float* __restrict__ scores, float* __restrict__ norm,
    int* __restrict__ counts, float* __restrict__ entr_out) {
    __shared__ float s_ent[BATCH];
    const int tid = threadIdx.x;
    for (int i = tid; i < BATCH * K_TOP * DIM; i += 256) counts[i] = 0;
    const int wid = tid >> 6, lane = tid & 63;
#pragma unroll
    for (int bb = 0; bb < 2; ++bb) {
        const int b = wid * 2 + bb;
        const float s0 = scores[b * DIM + lane];
        const float s1 = scores[b * DIM + 64 + lane];
        const float s2 = scores[b * DIM + 128 + lane];
        const float s3 = scores[b * DIM + 192 + lane];
        float mx = fmaxf(fmaxf(s0, s1), fmaxf(s2, s3));
        float mn = fminf(fminf(s0, s1), fminf(s2, s3));
#pragma unroll
        for (int off = 1; off < 64; off <<= 1) {
            mx = fmaxf(mx, __shfl_xor(mx, off, 64));
            mn = fminf(mn, __shfl_xor(mn, off, 64));
        }
        const float e0 = expf(s0 - mx), e1 = expf(s1 - mx);
        const float e2 = expf(s2 - mx), e3 = expf(s3 - mx);
        float se = e0 + e1 + e2 + e3;
#pragma unroll
        for (int off = 1; off < 64; off <<= 1) se += __shfl_xor(se, off, 64);
        const float lse = logf(se);
        float pl = e0 * ((s0 - mx) - lse) + e1 * ((s1 - mx) - lse) +
                   e2 * ((s2 - mx) - lse) + e3 * ((s3 - mx) - lse);
#pragma unroll
        for (int off = 1; off < 64; off <<= 1) pl += __shfl_xor(pl, off, 64);
        if (lane == 0) s_ent[b] = -(pl / se);
        const float den = mx - mn + 1e-5f;
        norm[b * DIM + lane]        = (s0 - mn) / den;
        norm[b * DIM + 64 + lane]   = (s1 - mn) / den;
        norm[b * DIM + 128 + lane]  = (s2 - mn) / den;
        norm[b * DIM + 192 + lane]  = (s3 - mn) / den;
    }
    __syncthreads();
    if (tid == 0) {
        float acc = 0.f;
#pragma unroll
        for (int b = 0; b < BATCH; ++b) acc += s_ent[b];
        entr_out[0] = acc * 0.125f;  // mean over 8 (exact /8)
    }
}

// ---------------------------------------------------------------------------
// Kernel 2: perturbed top-k.  One wave per (b, sample) row; 4 waves/block.
// ---------------------------------------------------------------------------
__global__ __launch_bounds__(256) void topk_kernel(
    const float* __restrict__ norm, int* __restrict__ counts) {
    const int wid = threadIdx.x >> 6;
    const int lane = threadIdx.x & 63;
    const int r = blockIdx.x * 4 + wid;  // 0..3999  (= b*500 + n)
    const int b = r / NSAMP;

    const uint32_t base = (uint32_t)r * 256u;
    float v0 = norm[b * DIM + lane]       + jax_normal_at(base + (uint32_t)lane)         * 0.05f;
    float v1 = norm[b * DIM + 64 + lane]  + jax_normal_at(base + 64u + (uint32_t)lane)   * 0.05f;
    float v2 = norm[b * DIM + 128 + lane] + jax_normal_at(base + 128u + (uint32_t)lane)  * 0.05f;
    float v3 = norm[b * DIM + 192 + lane] + jax_normal_at(base + 192u + (uint32_t)lane)  * 0.05f;

    int chosen[K_TOP];
#pragma unroll
    for (int it = 0; it < K_TOP; ++it) {
        float bv = v0; int bd = lane;
        { int d = 64 + lane;  if (v1 > bv || (v1 == bv && d < bd)) { bv = v1; bd = d; } }
        { int d = 128 + lane; if (v2 > bv || (v2 == bv && d < bd)) { bv = v2; bd = d; } }
        { int d = 192 + lane; if (v3 > bv || (v3 == bv && d < bd)) { bv = v3; bd = d; } }
#pragma unroll
        for (int off = 1; off < 64; off <<= 1) {
            float ov = __shfl_xor(bv, off, 64);
            int   od = __shfl_xor(bd, off, 64);
            if (ov > bv || (ov == bv && od < bd)) { bv = ov; bd = od; }
        }
        chosen[it] = bd;
        if ((bd & 63) == lane) {
            int q = bd >> 6;
            if (q == 0) v0 = -__builtin_inff();
            else if (q == 1) v1 = -__builtin_inff();
            else if (q == 2) v2 = -__builtin_inff();
            else v3 = -__builtin_inff();
        }
    }
    // sort 10 indices ascending (identical in every lane; static network)
#pragma unroll
    for (int a = 0; a < K_TOP - 1; ++a)
#pragma unroll
        for (int t = 0; t < K_TOP - 1 - a; ++t) {
            int x0 = chosen[t], x1 = chosen[t + 1];
            chosen[t] = min(x0, x1);
            chosen[t + 1] = max(x0, x1);
        }
    if (lane == 0) {
        const int cb = b * K_TOP * DIM;
#pragma unroll
        for (int k = 0; k < K_TOP; ++k)
            atomicAdd(&counts[cb + (k << 8) + chosen[k]], 1);
    }
}

// ---------------------------------------------------------------------------
// Kernel 3: per-batch union compaction of nonzero windows + 10-wide weights.
// 8 blocks x 64 lanes.
// ---------------------------------------------------------------------------
__global__ __launch_bounds__(64) void compact_union_kernel(
    const int* __restrict__ counts, int* __restrict__ u_ij,
    float* __restrict__ u_wt, int* __restrict__ u_n) {
    const int b = blockIdx.x;
    const int lane = threadIdx.x;
    int any0 = 0, any1 = 0, any2 = 0, any3 = 0;
    const int d0 = lane * 4;
#pragma unroll
    for (int k = 0; k < K_TOP; ++k) {
        const int* cb = counts + (b * K_TOP + k) * DIM;
        any0 |= cb[d0 + 0];
        any1 |= cb[d0 + 1];
        any2 |= cb[d0 + 2];
        any3 |= cb[d0 + 3];
    }
    int n = (any0 > 0) + (any1 > 0) + (any2 > 0) + (any3 > 0);
    int incl = n;
#pragma unroll
    for (int off = 1; off < 64; off <<= 1) {
        int t = __shfl_up(incl, off, 64);
        if (lane >= off) incl += t;
    }
    int pos = b * DIM + (incl - n);
#define EMIT(ANY, DD)                                                        \
    if (ANY > 0) {                                                           \
        u_ij[pos] = (DD);                                                    \
        _Pragma("unroll")                                                    \
        for (int k = 0; k < K_TOP; ++k)                                      \
            u_wt[pos * K_TOP + k] =                                          \
                (float)counts[(b * K_TOP + k) * DIM + (DD)] / 500.0f;        \
        pos++;                                                               \
    }
    EMIT(any0, d0 + 0)
    EMIT(any1, d0 + 1)
    EMIT(any2, d0 + 2)
    EMIT(any3, d0 + 3)
#undef EMIT
    if (lane == 63) u_n[b] = incl;
}

// ---------------------------------------------------------------------------
// Kernel 4: gather/accumulate patches. One wave per (b, c, 2-row chunk);
// no LDS, window idx + weights are wave-uniform -> scalar loads.
// grid = 8*3*64 = 1536 blocks x 64 threads (6 waves/CU).
// ---------------------------------------------------------------------------
__global__ __launch_bounds__(64) void gather_kernel(
    const float* __restrict__ x, const int* __restrict__ u_ij,
    const float* __restrict__ u_wt, const int* __restrict__ u_n,
    float* __restrict__ out) {
    const int blk = blockIdx.x;
    const int rc = blk & 63;        // rows h = rc*2, rc*2+1
    const int bc = blk >> 6;        // b*3 + c
    const int b = bc / 3;
    const int c = bc % 3;
    const int nnz = u_n[b];
    const int lane = threadIdx.x;
    const int h = (rc << 1) + (lane >> 5);
    const int w0 = (lane & 31) << 2;
    const float* img = x + (size_t)bc * (1024 * 1024);
    const int* __restrict__ ijp = u_ij + b * DIM;
    const float* __restrict__ wtp = u_wt + b * DIM * K_TOP;

    float4 acc[K_TOP];
#pragma unroll
    for (int k = 0; k < K_TOP; ++k) acc[k] = make_float4(0.f, 0.f, 0.f, 0.f);

    for (int tt = 0; tt < nnz; ++tt) {
        const int ij = ijp[tt];
        float wt[K_TOP];
#pragma unroll
        for (int k = 0; k < K_TOP; ++k) wt[k] = wtp[tt * K_TOP + k];
        const int i = ij >> 4, j = ij & 15;
        const int y = i * 64 + h - 32;
        const int xc = j * 64 + w0 - 32;  // multiple of 4 -> quads never split
        if ((unsigned)y < 1024u && (unsigned)xc < 1024u) {
            const float4 v = *(const float4*)(img + ((size_t)y << 10) + xc);
#pragma unroll
            for (int k = 0; k < K_TOP; ++k) {
                acc[k].x = fmaf(wt[k], v.x, acc[k].x);
                acc[k].y = fmaf(wt[k], v.y, acc[k].y);
                acc[k].z = fmaf(wt[k], v.z, acc[k].z);
                acc[k].w = fmaf(wt[k], v.w, acc[k].w);
            }
        }
    }
#pragma unroll
    for (int k = 0; k < K_TOP; ++k) {
        const size_t oidx =
            (((size_t)((b * K_TOP + k) * 3 + c)) << 14) + (h << 7) + w0;
        *(float4*)(out + oidx) = acc[k];
    }
}

// ---------------------------------------------------------------------------
extern "C" void kernel_launch(void* const* d_in, const int* in_sizes, int n_in,
                              void* d_out, int out_size, void* d_ws,
                              size_t ws_size, hipStream_t stream) {
    const float* x_high = (const float*)d_in[0];   // (8,3,1024,1024) f32
    const float* scores = (const float*)d_in[1];   // (8,16,16) f32
    float* out = (float*)d_out;                    // 3,932,160 patches + 1 entr

    // workspace layout
    float* norm  = (float*)d_ws;                         // 2048 f
    int*   counts = (int*)(norm + BATCH * DIM);          // 20480 i
    int*   u_ij  = counts + BATCH * K_TOP * DIM;         // 2048 i
    float* u_wt  = (float*)(u_ij + BATCH * DIM);         // 20480 f
    int*   u_n   = (int*)(u_wt + BATCH * DIM * K_TOP);   // 8 i

    scores_kernel<<<1, 256, 0, stream>>>(scores, norm, counts,
                                         out + PATCHES_ELEMS);
    topk_kernel<<<1000, 256, 0, stream>>>(norm, counts);
    compact_union_kernel<<<BATCH, 64, 0, stream>>>(counts, u_ij, u_wt, u_n);
    gather_kernel<<<BATCH * 3 * 64, 64, 0, stream>>>(x_high, u_ij, u_wt, u_n,
                                                     out);
}

// Round 10
// 177.775 us; speedup vs baseline: 1.2291x; 1.1094x over previous
//
#include <hip/hip_runtime.h>
#include <stdint.h>

#define K_TOP 10
#define NSAMP 500
#define DIM 256
#define BATCH 8
#define PATCHES_ELEMS (8LL * 10 * 3 * 128 * 128)  // 3,932,160

// ---------------------------------------------------------------------------
// Threefry-2x32, key = (0,1)  (jax.random.key(1) -> (0u, 1u))
// ---------------------------------------------------------------------------
__device__ __forceinline__ void threefry2x32_01(uint32_t x0, uint32_t x1,
                                                uint32_t& o0, uint32_t& o1) {
    const uint32_t ks0 = 0u;
    const uint32_t ks1 = 1u;
    const uint32_t ks2 = 0u ^ 1u ^ 0x1BD11BDAu;  // 0x1BD11BDB
    x0 += ks0; x1 += ks1;
#define TF_RND(r) { x0 += x1; x1 = (x1 << (r)) | (x1 >> (32 - (r))); x1 ^= x0; }
    TF_RND(13) TF_RND(15) TF_RND(26) TF_RND(6)
    x0 += ks1; x1 += ks2 + 1u;
    TF_RND(17) TF_RND(29) TF_RND(16) TF_RND(24)
    x0 += ks2; x1 += ks0 + 2u;
    TF_RND(13) TF_RND(15) TF_RND(26) TF_RND(6)
    x0 += ks0; x1 += ks1 + 3u;
    TF_RND(17) TF_RND(29) TF_RND(16) TF_RND(24)
    x0 += ks1; x1 += ks2 + 4u;
    TF_RND(13) TF_RND(15) TF_RND(26) TF_RND(6)
    x0 += ks2; x1 += ks0 + 5u;
#undef TF_RND
    o0 = x0; o1 = x1;
}

// XLA f32 ErfInv polynomial (Giles).
__device__ __forceinline__ float erfinv_xla(float x) {
    float w = -log1pf(-x * x);
    float p;
    if (w < 5.0f) {
        w = w - 2.5f;
        p = 2.81022636e-08f;
        p = fmaf(p, w, 3.43273939e-07f);
        p = fmaf(p, w, -3.5233877e-06f);
        p = fmaf(p, w, -4.39150654e-06f);
        p = fmaf(p, w, 0.00021858087f);
        p = fmaf(p, w, -0.00125372503f);
        p = fmaf(p, w, -0.00417768164f);
        p = fmaf(p, w, 0.246640727f);
        p = fmaf(p, w, 1.50140941f);
    } else {
        w = sqrtf(w) - 3.0f;
        p = -0.000200214257f;
        p = fmaf(p, w, 0.000100950558f);
        p = fmaf(p, w, 0.00134934322f);
        p = fmaf(p, w, -0.00367342844f);
        p = fmaf(p, w, 0.00573950773f);
        p = fmaf(p, w, -0.0076224613f);
        p = fmaf(p, w, 0.00943887047f);
        p = fmaf(p, w, 1.00167406f);
        p = fmaf(p, w, 2.83297682f);
    }
    return p * x;
}

// jax_threefry_partitionable: bits = o0 ^ o1 of threefry(key, (0, flat)).
// VERIFIED on HW round 6: absmax 0.0078 -> exact RNG realization.
__device__ __forceinline__ float jax_normal_at(uint32_t flat) {
    uint32_t o0, o1;
    threefry2x32_01(0u, flat, o0, o1);
    uint32_t bits = o0 ^ o1;
    float f = __uint_as_float((bits >> 9) | 0x3f800000u) - 1.0f;  // [0,1)
    const float lo = -0.99999994f;  // nextafter(-1,0) in f32
    float u = fmaxf(lo, fmaf(f, 2.0f, lo));  // hi-lo rounds to exactly 2.0f
    return 1.4142135381698608f * erfinv_xla(u);  // float32(sqrt(2))
}

// ---------------------------------------------------------------------------
// Kernel 1: entropy + normalize + zero counts.  One block, wave-parallel.
// ---------------------------------------------------------------------------
__global__ __launch_bounds__(256) void scores_kernel(
    const float* __restrict__ scores, float* __restrict__ norm,
    int* __restrict__ counts, float* __restrict__ entr_out) {
    __shared__ float s_ent[BATCH];
    const int tid = threadIdx.x;
    for (int i = tid; i < BATCH * K_TOP * DIM; i += 256) counts[i] = 0;
    const int wid = tid >> 6, lane = tid & 63;
#pragma unroll
    for (int bb = 0; bb < 2; ++bb) {
        const int b = wid * 2 + bb;
        const float s0 = scores[b * DIM + lane];
        const float s1 = scores[b * DIM + 64 + lane];
        const float s2 = scores[b * DIM + 128 + lane];
        const float s3 = scores[b * DIM + 192 + lane];
        float mx = fmaxf(fmaxf(s0, s1), fmaxf(s2, s3));
        float mn = fminf(fminf(s0, s1), fminf(s2, s3));
#pragma unroll
        for (int off = 1; off < 64; off <<= 1) {
            mx = fmaxf(mx, __shfl_xor(mx, off, 64));
            mn = fminf(mn, __shfl_xor(mn, off, 64));
        }
        const float e0 = expf(s0 - mx), e1 = expf(s1 - mx);
        const float e2 = expf(s2 - mx), e3 = expf(s3 - mx);
        float se = e0 + e1 + e2 + e3;
#pragma unroll
        for (int off = 1; off < 64; off <<= 1) se += __shfl_xor(se, off, 64);
        const float lse = logf(se);
        float pl = e0 * ((s0 - mx) - lse) + e1 * ((s1 - mx) - lse) +
                   e2 * ((s2 - mx) - lse) + e3 * ((s3 - mx) - lse);
#pragma unroll
        for (int off = 1; off < 64; off <<= 1) pl += __shfl_xor(pl, off, 64);
        if (lane == 0) s_ent[b] = -(pl / se);
        const float den = mx - mn + 1e-5f;
        norm[b * DIM + lane]        = (s0 - mn) / den;
        norm[b * DIM + 64 + lane]   = (s1 - mn) / den;
        norm[b * DIM + 128 + lane]  = (s2 - mn) / den;
        norm[b * DIM + 192 + lane]  = (s3 - mn) / den;
    }
    __syncthreads();
    if (tid == 0) {
        float acc = 0.f;
#pragma unroll
        for (int b = 0; b < BATCH; ++b) acc += s_ent[b];
        entr_out[0] = acc * 0.125f;  // mean over 8 (exact /8)
    }
}

// ---------------------------------------------------------------------------
// Kernel 2: perturbed top-k.  One wave per (b, sample) row; 4 waves/block.
// ---------------------------------------------------------------------------
__global__ __launch_bounds__(256) void topk_kernel(
    const float* __restrict__ norm, int* __restrict__ counts) {
    const int wid = threadIdx.x >> 6;
    const int lane = threadIdx.x & 63;
    const int r = blockIdx.x * 4 + wid;  // 0..3999  (= b*500 + n)
    const int b = r / NSAMP;

    const uint32_t base = (uint32_t)r * 256u;
    float v0 = norm[b * DIM + lane]       + jax_normal_at(base + (uint32_t)lane)         * 0.05f;
    float v1 = norm[b * DIM + 64 + lane]  + jax_normal_at(base + 64u + (uint32_t)lane)   * 0.05f;
    float v2 = norm[b * DIM + 128 + lane] + jax_normal_at(base + 128u + (uint32_t)lane)  * 0.05f;
    float v3 = norm[b * DIM + 192 + lane] + jax_normal_at(base + 192u + (uint32_t)lane)  * 0.05f;

    int chosen[K_TOP];
#pragma unroll
    for (int it = 0; it < K_TOP; ++it) {
        float bv = v0; int bd = lane;
        { int d = 64 + lane;  if (v1 > bv || (v1 == bv && d < bd)) { bv = v1; bd = d; } }
        { int d = 128 + lane; if (v2 > bv || (v2 == bv && d < bd)) { bv = v2; bd = d; } }
        { int d = 192 + lane; if (v3 > bv || (v3 == bv && d < bd)) { bv = v3; bd = d; } }
#pragma unroll
        for (int off = 1; off < 64; off <<= 1) {
            float ov = __shfl_xor(bv, off, 64);
            int   od = __shfl_xor(bd, off, 64);
            if (ov > bv || (ov == bv && od < bd)) { bv = ov; bd = od; }
        }
        chosen[it] = bd;
        if ((bd & 63) == lane) {
            int q = bd >> 6;
            if (q == 0) v0 = -__builtin_inff();
            else if (q == 1) v1 = -__builtin_inff();
            else if (q == 2) v2 = -__builtin_inff();
            else v3 = -__builtin_inff();
        }
    }
    // sort 10 indices ascending (identical in every lane; static network)
#pragma unroll
    for (int a = 0; a < K_TOP - 1; ++a)
#pragma unroll
        for (int t = 0; t < K_TOP - 1 - a; ++t) {
            int x0 = chosen[t], x1 = chosen[t + 1];
            chosen[t] = min(x0, x1);
            chosen[t + 1] = max(x0, x1);
        }
    if (lane == 0) {
        const int cb = b * K_TOP * DIM;
#pragma unroll
        for (int k = 0; k < K_TOP; ++k)
            atomicAdd(&counts[cb + (k << 8) + chosen[k]], 1);
    }
}

// ---------------------------------------------------------------------------
// Kernel 3: per-batch union compaction of nonzero windows + 10-wide weights.
// 8 blocks x 64 lanes.
// ---------------------------------------------------------------------------
__global__ __launch_bounds__(64) void compact_union_kernel(
    const int* __restrict__ counts, int* __restrict__ u_ij,
    float* __restrict__ u_wt, int* __restrict__ u_n) {
    const int b = blockIdx.x;
    const int lane = threadIdx.x;
    int any0 = 0, any1 = 0, any2 = 0, any3 = 0;
    const int d0 = lane * 4;
#pragma unroll
    for (int k = 0; k < K_TOP; ++k) {
        const int* cb = counts + (b * K_TOP + k) * DIM;
        any0 |= cb[d0 + 0];
        any1 |= cb[d0 + 1];
        any2 |= cb[d0 + 2];
        any3 |= cb[d0 + 3];
    }
    int n = (any0 > 0) + (any1 > 0) + (any2 > 0) + (any3 > 0);
    int incl = n;
#pragma unroll
    for (int off = 1; off < 64; off <<= 1) {
        int t = __shfl_up(incl, off, 64);
        if (lane >= off) incl += t;
    }
    int pos = b * DIM + (incl - n);
#define EMIT(ANY, DD)                                                        \
    if (ANY > 0) {                                                           \
        u_ij[pos] = (DD);                                                    \
        _Pragma("unroll")                                                    \
        for (int k = 0; k < K_TOP; ++k)                                      \
            u_wt[pos * K_TOP + k] =                                          \
                (float)counts[(b * K_TOP + k) * DIM + (DD)] / 500.0f;        \
        pos++;                                                               \
    }
    EMIT(any0, d0 + 0)
    EMIT(any1, d0 + 1)
    EMIT(any2, d0 + 2)
    EMIT(any3, d0 + 3)
#undef EMIT
    if (lane == 63) u_n[b] = incl;
}

// ---------------------------------------------------------------------------
// Kernel 4: gather/accumulate patches. Block = 256 thr (4 waves) per
// (b, c, 2-row chunk). Waves stride the window list (tt = wid, wid+4, ...)
// -> 4x latency hiding; partial acc combined via 2-stage LDS tree.
// grid = 8*3*64 = 1536 blocks.
// ---------------------------------------------------------------------------
__global__ __launch_bounds__(256) void gather_kernel(
    const float* __restrict__ x, const int* __restrict__ u_ij,
    const float* __restrict__ u_wt, const int* __restrict__ u_n,
    float* __restrict__ out) {
    // [stage][k][lane] float4: per-k slice is 64x16B contiguous -> no bank
    // conflicts on ds_read_b128/ds_write_b128.
    __shared__ float4 lds[2][K_TOP][64];

    const int blk = blockIdx.x;
    const int rc = blk & 63;        // rows h = rc*2, rc*2+1
    const int bc = blk >> 6;        // b*3 + c
    const int b = bc / 3;
    const int c = bc % 3;
    const int nnz = u_n[b];
    const int tid = threadIdx.x;
    const int wid = tid >> 6, lane = tid & 63;
    const int h = (rc << 1) + (lane >> 5);
    const int w0 = (lane & 31) << 2;
    const float* img = x + (size_t)bc * (1024 * 1024);
    const int* __restrict__ ijp = u_ij + b * DIM;
    const float* __restrict__ wtp = u_wt + b * DIM * K_TOP;

    float4 acc[K_TOP];
#pragma unroll
    for (int k = 0; k < K_TOP; ++k) acc[k] = make_float4(0.f, 0.f, 0.f, 0.f);

    for (int tt = wid; tt < nnz; tt += 4) {
        const int ij = ijp[tt];
        float wt[K_TOP];
#pragma unroll
        for (int k = 0; k < K_TOP; ++k) wt[k] = wtp[tt * K_TOP + k];
        const int i = ij >> 4, j = ij & 15;
        const int y = i * 64 + h - 32;
        const int xc = j * 64 + w0 - 32;  // multiple of 4 -> quads never split
        if ((unsigned)y < 1024u && (unsigned)xc < 1024u) {
            const float4 v = *(const float4*)(img + ((size_t)y << 10) + xc);
#pragma unroll
            for (int k = 0; k < K_TOP; ++k) {
                acc[k].x = fmaf(wt[k], v.x, acc[k].x);
                acc[k].y = fmaf(wt[k], v.y, acc[k].y);
                acc[k].z = fmaf(wt[k], v.z, acc[k].z);
                acc[k].w = fmaf(wt[k], v.w, acc[k].w);
            }
        }
    }

    // stage 1: waves 2,3 -> LDS; waves 0,1 add
    if (wid >= 2) {
#pragma unroll
        for (int k = 0; k < K_TOP; ++k) lds[wid - 2][k][lane] = acc[k];
    }
    __syncthreads();
    if (wid < 2) {
#pragma unroll
        for (int k = 0; k < K_TOP; ++k) {
            const float4 t = lds[wid][k][lane];
            acc[k].x += t.x; acc[k].y += t.y; acc[k].z += t.z; acc[k].w += t.w;
        }
    }
    __syncthreads();
    // stage 2: wave 1 -> LDS; wave 0 adds and writes out
    if (wid == 1) {
#pragma unroll
        for (int k = 0; k < K_TOP; ++k) lds[0][k][lane] = acc[k];
    }
    __syncthreads();
    if (wid == 0) {
#pragma unroll
        for (int k = 0; k < K_TOP; ++k) {
            const float4 t = lds[0][k][lane];
            acc[k].x += t.x; acc[k].y += t.y; acc[k].z += t.z; acc[k].w += t.w;
            const size_t oidx =
                (((size_t)((b * K_TOP + k) * 3 + c)) << 14) + (h << 7) + w0;
            *(float4*)(out + oidx) = acc[k];
        }
    }
}

// ---------------------------------------------------------------------------
extern "C" void kernel_launch(void* const* d_in, const int* in_sizes, int n_in,
                              void* d_out, int out_size, void* d_ws,
                              size_t ws_size, hipStream_t stream) {
    const float* x_high = (const float*)d_in[0];   // (8,3,1024,1024) f32
    const float* scores = (const float*)d_in[1];   // (8,16,16) f32
    float* out = (float*)d_out;                    // 3,932,160 patches + 1 entr

    // workspace layout
    float* norm  = (float*)d_ws;                         // 2048 f
    int*   counts = (int*)(norm + BATCH * DIM);          // 20480 i
    int*   u_ij  = counts + BATCH * K_TOP * DIM;         // 2048 i
    float* u_wt  = (float*)(u_ij + BATCH * DIM);         // 20480 f
    int*   u_n   = (int*)(u_wt + BATCH * DIM * K_TOP);   // 8 i

    scores_kernel<<<1, 256, 0, stream>>>(scores, norm, counts,
                                         out + PATCHES_ELEMS);
    topk_kernel<<<1000, 256, 0, stream>>>(norm, counts);
    compact_union_kernel<<<BATCH, 64, 0, stream>>>(counts, u_ij, u_wt, u_n);
    gather_kernel<<<BATCH * 3 * 64, 256, 0, stream>>>(x_high, u_ij, u_wt, u_n,
                                                      out);
}

// Round 13
// 171.875 us; speedup vs baseline: 1.2712x; 1.0343x over previous
//
#include <hip/hip_runtime.h>
#include <stdint.h>

#define K_TOP 10
#define NSAMP 500
#define DIM 256
#define BATCH 8
#define WSTRIDE 12  // padded weight stride in LDS (16B-aligned reads)
#define PATCHES_ELEMS (8LL * 10 * 3 * 128 * 128)  // 3,932,160

// ---------------------------------------------------------------------------
// Threefry-2x32, key = (0,1)  (jax.random.key(1) -> (0u, 1u))
// ---------------------------------------------------------------------------
__device__ __forceinline__ void threefry2x32_01(uint32_t x0, uint32_t x1,
                                                uint32_t& o0, uint32_t& o1) {
    const uint32_t ks0 = 0u;
    const uint32_t ks1 = 1u;
    const uint32_t ks2 = 0u ^ 1u ^ 0x1BD11BDAu;  // 0x1BD11BDB
    x0 += ks0; x1 += ks1;
#define TF_RND(r) { x0 += x1; x1 = (x1 << (r)) | (x1 >> (32 - (r))); x1 ^= x0; }
    TF_RND(13) TF_RND(15) TF_RND(26) TF_RND(6)
    x0 += ks1; x1 += ks2 + 1u;
    TF_RND(17) TF_RND(29) TF_RND(16) TF_RND(24)
    x0 += ks2; x1 += ks0 + 2u;
    TF_RND(13) TF_RND(15) TF_RND(26) TF_RND(6)
    x0 += ks0; x1 += ks1 + 3u;
    TF_RND(17) TF_RND(29) TF_RND(16) TF_RND(24)
    x0 += ks1; x1 += ks2 + 4u;
    TF_RND(13) TF_RND(15) TF_RND(26) TF_RND(6)
    x0 += ks2; x1 += ks0 + 5u;
#undef TF_RND
    o0 = x0; o1 = x1;
}

// XLA f32 ErfInv polynomial (Giles).
__device__ __forceinline__ float erfinv_xla(float x) {
    float w = -log1pf(-x * x);
    float p;
    if (w < 5.0f) {
        w = w - 2.5f;
        p = 2.81022636e-08f;
        p = fmaf(p, w, 3.43273939e-07f);
        p = fmaf(p, w, -3.5233877e-06f);
        p = fmaf(p, w, -4.39150654e-06f);
        p = fmaf(p, w, 0.00021858087f);
        p = fmaf(p, w, -0.00125372503f);
        p = fmaf(p, w, -0.00417768164f);
        p = fmaf(p, w, 0.246640727f);
        p = fmaf(p, w, 1.50140941f);
    } else {
        w = sqrtf(w) - 3.0f;
        p = -0.000200214257f;
        p = fmaf(p, w, 0.000100950558f);
        p = fmaf(p, w, 0.00134934322f);
        p = fmaf(p, w, -0.00367342844f);
        p = fmaf(p, w, 0.00573950773f);
        p = fmaf(p, w, -0.0076224613f);
        p = fmaf(p, w, 0.00943887047f);
        p = fmaf(p, w, 1.00167406f);
        p = fmaf(p, w, 2.83297682f);
    }
    return p * x;
}

// jax_threefry_partitionable: bits = o0 ^ o1 of threefry(key, (0, flat)).
// VERIFIED on HW round 6: absmax 0.0078 -> exact RNG realization.
__device__ __forceinline__ float jax_normal_at(uint32_t flat) {
    uint32_t o0, o1;
    threefry2x32_01(0u, flat, o0, o1);
    uint32_t bits = o0 ^ o1;
    float f = __uint_as_float((bits >> 9) | 0x3f800000u) - 1.0f;  // [0,1)
    const float lo = -0.99999994f;  // nextafter(-1,0) in f32
    float u = fmaxf(lo, fmaf(f, 2.0f, lo));  // hi-lo rounds to exactly 2.0f
    return 1.4142135381698608f * erfinv_xla(u);  // float32(sqrt(2))
}

// ---------------------------------------------------------------------------
// Kernel 1: entropy + normalize + zero counts.  One block, wave-parallel.
// ---------------------------------------------------------------------------
__global__ __launch_bounds__(256) void scores_kernel(
    const float* __restrict__ scores, float* __restrict__ norm,
    int* __restrict__ counts, float* __restrict__ entr_out) {
    __shared__ float s_ent[BATCH];
    const int tid = threadIdx.x;
    for (int i = tid; i < BATCH * K_TOP * DIM; i += 256) counts[i] = 0;
    const int wid = tid >> 6, lane = tid & 63;
#pragma unroll
    for (int bb = 0; bb < 2; ++bb) {
        const int b = wid * 2 + bb;
        const float s0 = scores[b * DIM + lane];
        const float s1 = scores[b * DIM + 64 + lane];
        const float s2 = scores[b * DIM + 128 + lane];
        const float s3 = scores[b * DIM + 192 + lane];
        float mx = fmaxf(fmaxf(s0, s1), fmaxf(s2, s3));
        float mn = fminf(fminf(s0, s1), fminf(s2, s3));
#pragma unroll
        for (int off = 1; off < 64; off <<= 1) {
            mx = fmaxf(mx, __shfl_xor(mx, off, 64));
            mn = fminf(mn, __shfl_xor(mn, off, 64));
        }
        const float e0 = expf(s0 - mx), e1 = expf(s1 - mx);
        const float e2 = expf(s2 - mx), e3 = expf(s3 - mx);
        float se = e0 + e1 + e2 + e3;
#pragma unroll
        for (int off = 1; off < 64; off <<= 1) se += __shfl_xor(se, off, 64);
        const float lse = logf(se);
        float pl = e0 * ((s0 - mx) - lse) + e1 * ((s1 - mx) - lse) +
                   e2 * ((s2 - mx) - lse) + e3 * ((s3 - mx) - lse);
#pragma unroll
        for (int off = 1; off < 64; off <<= 1) pl += __shfl_xor(pl, off, 64);
        if (lane == 0) s_ent[b] = -(pl / se);
        const float den = mx - mn + 1e-5f;
        norm[b * DIM + lane]        = (s0 - mn) / den;
        norm[b * DIM + 64 + lane]   = (s1 - mn) / den;
        norm[b * DIM + 128 + lane]  = (s2 - mn) / den;
        norm[b * DIM + 192 + lane]  = (s3 - mn) / den;
    }
    __syncthreads();
    if (tid == 0) {
        float acc = 0.f;
#pragma unroll
        for (int b = 0; b < BATCH; ++b) acc += s_ent[b];
        entr_out[0] = acc * 0.125f;  // mean over 8 (exact /8)
    }
}

// ---------------------------------------------------------------------------
// Kernel 2: perturbed top-k.  One wave per (b, sample) row; 4 waves/block.
// ---------------------------------------------------------------------------
__global__ __launch_bounds__(256) void topk_kernel(
    const float* __restrict__ norm, int* __restrict__ counts) {
    const int wid = threadIdx.x >> 6;
    const int lane = threadIdx.x & 63;
    const int r = blockIdx.x * 4 + wid;  // 0..3999  (= b*500 + n)
    const int b = r / NSAMP;

    const uint32_t base = (uint32_t)r * 256u;
    float v0 = norm[b * DIM + lane]       + jax_normal_at(base + (uint32_t)lane)         * 0.05f;
    float v1 = norm[b * DIM + 64 + lane]  + jax_normal_at(base + 64u + (uint32_t)lane)   * 0.05f;
    float v2 = norm[b * DIM + 128 + lane] + jax_normal_at(base + 128u + (uint32_t)lane)  * 0.05f;
    float v3 = norm[b * DIM + 192 + lane] + jax_normal_at(base + 192u + (uint32_t)lane)  * 0.05f;

    int chosen[K_TOP];
#pragma unroll
    for (int it = 0; it < K_TOP; ++it) {
        float bv = v0; int bd = lane;
        { int d = 64 + lane;  if (v1 > bv || (v1 == bv && d < bd)) { bv = v1; bd = d; } }
        { int d = 128 + lane; if (v2 > bv || (v2 == bv && d < bd)) { bv = v2; bd = d; } }
        { int d = 192 + lane; if (v3 > bv || (v3 == bv && d < bd)) { bv = v3; bd = d; } }
#pragma unroll
        for (int off = 1; off < 64; off <<= 1) {
            float ov = __shfl_xor(bv, off, 64);
            int   od = __shfl_xor(bd, off, 64);
            if (ov > bv || (ov == bv && od < bd)) { bv = ov; bd = od; }
        }
        chosen[it] = bd;
        if ((bd & 63) == lane) {
            int q = bd >> 6;
            if (q == 0) v0 = -__builtin_inff();
            else if (q == 1) v1 = -__builtin_inff();
            else if (q == 2) v2 = -__builtin_inff();
            else v3 = -__builtin_inff();
        }
    }
    // sort 10 indices ascending (identical in every lane; static network)
#pragma unroll
    for (int a = 0; a < K_TOP - 1; ++a)
#pragma unroll
        for (int t = 0; t < K_TOP - 1 - a; ++t) {
            int x0 = chosen[t], x1 = chosen[t + 1];
            chosen[t] = min(x0, x1);
            chosen[t + 1] = max(x0, x1);
        }
    if (lane == 0) {
        const int cb = b * K_TOP * DIM;
#pragma unroll
        for (int k = 0; k < K_TOP; ++k)
            atomicAdd(&counts[cb + (k << 8) + chosen[k]], 1);
    }
}

// ---------------------------------------------------------------------------
// Kernel 3: per-batch union compaction of nonzero windows + 10-wide weights.
// 8 blocks x 64 lanes.
// ---------------------------------------------------------------------------
__global__ __launch_bounds__(64) void compact_union_kernel(
    const int* __restrict__ counts, int* __restrict__ u_ij,
    float* __restrict__ u_wt, int* __restrict__ u_n) {
    const int b = blockIdx.x;
    const int lane = threadIdx.x;
    int any0 = 0, any1 = 0, any2 = 0, any3 = 0;
    const int d0 = lane * 4;
#pragma unroll
    for (int k = 0; k < K_TOP; ++k) {
        const int* cb = counts + (b * K_TOP + k) * DIM;
        any0 |= cb[d0 + 0];
        any1 |= cb[d0 + 1];
        any2 |= cb[d0 + 2];
        any3 |= cb[d0 + 3];
    }
    int n = (any0 > 0) + (any1 > 0) + (any2 > 0) + (any3 > 0);
    int incl = n;
#pragma unroll
    for (int off = 1; off < 64; off <<= 1) {
        int t = __shfl_up(incl, off, 64);
        if (lane >= off) incl += t;
    }
    int pos = b * DIM + (incl - n);
#define EMIT(ANY, DD)                                                        \
    if (ANY > 0) {                                                           \
        u_ij[pos] = (DD);                                                    \
        _Pragma("unroll")                                                    \
        for (int k = 0; k < K_TOP; ++k)                                      \
            u_wt[pos * K_TOP + k] =                                          \
                (float)counts[(b * K_TOP + k) * DIM + (DD)] / 500.0f;        \
        pos++;                                                               \
    }
    EMIT(any0, d0 + 0)
    EMIT(any1, d0 + 1)
    EMIT(any2, d0 + 2)
    EMIT(any3, d0 + 3)
#undef EMIT
    if (lane == 63) u_n[b] = incl;
}

// ---------------------------------------------------------------------------
// 10-way FMA of one float4 against the 10 window weights (LDS, padded to 12).
// ---------------------------------------------------------------------------
__device__ __forceinline__ void fma10(float4 acc[K_TOP], const float4 v,
                                      const float* __restrict__ w12) {
    const float4 wA = *(const float4*)(w12);
    const float4 wB = *(const float4*)(w12 + 4);
    const float2 wC = *(const float2*)(w12 + 8);
    const float wk[K_TOP] = {wA.x, wA.y, wA.z, wA.w,
                             wB.x, wB.y, wB.z, wB.w, wC.x, wC.y};
#pragma unroll
    for (int k = 0; k < K_TOP; ++k) {
        acc[k].x = fmaf(wk[k], v.x, acc[k].x);
        acc[k].y = fmaf(wk[k], v.y, acc[k].y);
        acc[k].z = fmaf(wk[k], v.z, acc[k].z);
        acc[k].w = fmaf(wk[k], v.w, acc[k].w);
    }
}

// ---------------------------------------------------------------------------
// Kernel 4: gather/accumulate patches. Block = 256 thr (4 waves) per
// (b, c, 2-row chunk). Descriptors staged in LDS (aliased onto the reduction
// tree buffer); waves process stride-8 PAIRS of windows (2 image loads in
// flight); loop-body global traffic = image float4 only.
// grid = 8*3*64 = 1536 blocks.
// ---------------------------------------------------------------------------
__global__ __launch_bounds__(256) void gather_kernel(
    const float* __restrict__ x, const int* __restrict__ u_ij,
    const float* __restrict__ u_wt, const int* __restrict__ u_n,
    float* __restrict__ out) {
    // 20 KB tree buffer; first 13 KB aliased as descriptor staging during the
    // main loop (all staging reads complete before the tree phase's barrier).
    __shared__ float4 ldsbuf[2][K_TOP][64];
    int*   s_ij = (int*)&ldsbuf[0][0][0];       // [256]
    float* s_wt = (float*)(s_ij + DIM);         // [256*WSTRIDE]

    const int blk = blockIdx.x;
    const int rc = blk & 63;        // rows h = rc*2, rc*2+1
    const int bc = blk >> 6;        // b*3 + c
    const int b = bc / 3;
    const int c = bc % 3;
    const int nnz = u_n[b];
    const int tid = threadIdx.x;
    const int wid = tid >> 6, lane = tid & 63;
    const int h = (rc << 1) + (lane >> 5);
    const int w0 = (lane & 31) << 2;
    const float* img = x + (size_t)bc * (1024 * 1024);

    // stage descriptors (coalesced, once per block)
    for (int i = tid; i < nnz; i += 256) s_ij[i] = u_ij[b * DIM + i];
    for (int i = tid; i < nnz * K_TOP; i += 256) {
        const int t = i / K_TOP, k = i - t * K_TOP;
        s_wt[t * WSTRIDE + k] = u_wt[b * DIM * K_TOP + i];
    }
    __syncthreads();

    float4 acc[K_TOP];
#pragma unroll
    for (int k = 0; k < K_TOP; ++k) acc[k] = make_float4(0.f, 0.f, 0.f, 0.f);

    // stride-8 pairs: wave w handles {2w, 2w+1, 2w+8, 2w+9, ...}
    for (int t0 = wid * 2; t0 < nnz; t0 += 8) {
        const int t1 = t0 + 1;          // wave-uniform validity
        const int ij0 = s_ij[t0];
        const int y0  = (ij0 >> 4) * 64 + h - 32;
        const int xc0 = (ij0 & 15) * 64 + w0 - 32;
        float4 v0 = make_float4(0.f, 0.f, 0.f, 0.f);
        if ((unsigned)y0 < 1024u && (unsigned)xc0 < 1024u)
            v0 = *(const float4*)(img + ((size_t)y0 << 10) + xc0);

        if (t1 < nnz) {
            const int ij1 = s_ij[t1];
            const int y1  = (ij1 >> 4) * 64 + h - 32;
            const int xc1 = (ij1 & 15) * 64 + w0 - 32;
            float4 v1 = make_float4(0.f, 0.f, 0.f, 0.f);
            if ((unsigned)y1 < 1024u && (unsigned)xc1 < 1024u)
                v1 = *(const float4*)(img + ((size_t)y1 << 10) + xc1);
            fma10(acc, v0, &s_wt[t0 * WSTRIDE]);
            fma10(acc, v1, &s_wt[t1 * WSTRIDE]);
        } else {
            fma10(acc, v0, &s_wt[t0 * WSTRIDE]);
        }
    }

    // tree combine (ldsbuf reuse is safe: barrier orders staging reads first)
    __syncthreads();
    if (wid >= 2) {
#pragma unroll
        for (int k = 0; k < K_TOP; ++k) ldsbuf[wid - 2][k][lane] = acc[k];
    }
    __syncthreads();
    if (wid < 2) {
#pragma unroll
        for (int k = 0; k < K_TOP; ++k) {
            const float4 t = ldsbuf[wid][k][lane];
            acc[k].x += t.x; acc[k].y += t.y; acc[k].z += t.z; acc[k].w += t.w;
        }
    }
    __syncthreads();
    if (wid == 1) {
#pragma unroll
        for (int k = 0; k < K_TOP; ++k) ldsbuf[0][k][lane] = acc[k];
    }
    __syncthreads();
    if (wid == 0) {
#pragma unroll
        for (int k = 0; k < K_TOP; ++k) {
            const float4 t = ldsbuf[0][k][lane];
            acc[k].x += t.x; acc[k].y += t.y; acc[k].z += t.z; acc[k].w += t.w;
            const size_t oidx =
                (((size_t)((b * K_TOP + k) * 3 + c)) << 14) + (h << 7) + w0;
            *(float4*)(out + oidx) = acc[k];
        }
    }
}

// ---------------------------------------------------------------------------
extern "C" void kernel_launch(void* const* d_in, const int* in_sizes, int n_in,
                              void* d_out, int out_size, void* d_ws,
                              size_t ws_size, hipStream_t stream) {
    const float* x_high = (const float*)d_in[0];   // (8,3,1024,1024) f32
    const float* scores = (const float*)d_in[1];   // (8,16,16) f32
    float* out = (float*)d_out;                    // 3,932,160 patches + 1 entr

    // workspace layout
    float* norm  = (float*)d_ws;                         // 2048 f
    int*   counts = (int*)(norm + BATCH * DIM);          // 20480 i
    int*   u_ij  = counts + BATCH * K_TOP * DIM;         // 2048 i
    float* u_wt  = (float*)(u_ij + BATCH * DIM);         // 20480 f
    int*   u_n   = (int*)(u_wt + BATCH * DIM * K_TOP);   // 8 i

    scores_kernel<<<1, 256, 0, stream>>>(scores, norm, counts,
                                         out + PATCHES_ELEMS);
    topk_kernel<<<1000, 256, 0, stream>>>(norm, counts);
    compact_union_kernel<<<BATCH, 64, 0, stream>>>(counts, u_ij, u_wt, u_n);
    gather_kernel<<<BATCH * 3 * 64, 256, 0, stream>>>(x_high, u_ij, u_wt, u_n,
                                                      out);
}

// Round 14
// 165.499 us; speedup vs baseline: 1.3202x; 1.0385x over previous
//
#include <hip/hip_runtime.h>
#include <stdint.h>

#define K_TOP 10
#define NSAMP 500
#define DIM 256
#define BATCH 8
#define WSTRIDE 12  // padded weight stride in LDS (16B-aligned reads)
#define PATCHES_ELEMS (8LL * 10 * 3 * 128 * 128)  // 3,932,160

// ---------------------------------------------------------------------------
// Threefry-2x32, key = (0,1)  (jax.random.key(1) -> (0u, 1u))
// ---------------------------------------------------------------------------
__device__ __forceinline__ void threefry2x32_01(uint32_t x0, uint32_t x1,
                                                uint32_t& o0, uint32_t& o1) {
    const uint32_t ks0 = 0u;
    const uint32_t ks1 = 1u;
    const uint32_t ks2 = 0u ^ 1u ^ 0x1BD11BDAu;  // 0x1BD11BDB
    x0 += ks0; x1 += ks1;
#define TF_RND(r) { x0 += x1; x1 = (x1 << (r)) | (x1 >> (32 - (r))); x1 ^= x0; }
    TF_RND(13) TF_RND(15) TF_RND(26) TF_RND(6)
    x0 += ks1; x1 += ks2 + 1u;
    TF_RND(17) TF_RND(29) TF_RND(16) TF_RND(24)
    x0 += ks2; x1 += ks0 + 2u;
    TF_RND(13) TF_RND(15) TF_RND(26) TF_RND(6)
    x0 += ks0; x1 += ks1 + 3u;
    TF_RND(17) TF_RND(29) TF_RND(16) TF_RND(24)
    x0 += ks1; x1 += ks2 + 4u;
    TF_RND(13) TF_RND(15) TF_RND(26) TF_RND(6)
    x0 += ks2; x1 += ks0 + 5u;
#undef TF_RND
    o0 = x0; o1 = x1;
}

// XLA f32 ErfInv polynomial (Giles).
__device__ __forceinline__ float erfinv_xla(float x) {
    float w = -log1pf(-x * x);
    float p;
    if (w < 5.0f) {
        w = w - 2.5f;
        p = 2.81022636e-08f;
        p = fmaf(p, w, 3.43273939e-07f);
        p = fmaf(p, w, -3.5233877e-06f);
        p = fmaf(p, w, -4.39150654e-06f);
        p = fmaf(p, w, 0.00021858087f);
        p = fmaf(p, w, -0.00125372503f);
        p = fmaf(p, w, -0.00417768164f);
        p = fmaf(p, w, 0.246640727f);
        p = fmaf(p, w, 1.50140941f);
    } else {
        w = sqrtf(w) - 3.0f;
        p = -0.000200214257f;
        p = fmaf(p, w, 0.000100950558f);
        p = fmaf(p, w, 0.00134934322f);
        p = fmaf(p, w, -0.00367342844f);
        p = fmaf(p, w, 0.00573950773f);
        p = fmaf(p, w, -0.0076224613f);
        p = fmaf(p, w, 0.00943887047f);
        p = fmaf(p, w, 1.00167406f);
        p = fmaf(p, w, 2.83297682f);
    }
    return p * x;
}

// jax_threefry_partitionable: bits = o0 ^ o1 of threefry(key, (0, flat)).
// VERIFIED on HW round 6: absmax 0.0078 -> exact RNG realization.
__device__ __forceinline__ float jax_normal_at(uint32_t flat) {
    uint32_t o0, o1;
    threefry2x32_01(0u, flat, o0, o1);
    uint32_t bits = o0 ^ o1;
    float f = __uint_as_float((bits >> 9) | 0x3f800000u) - 1.0f;  // [0,1)
    const float lo = -0.99999994f;  // nextafter(-1,0) in f32
    float u = fmaxf(lo, fmaf(f, 2.0f, lo));  // hi-lo rounds to exactly 2.0f
    return 1.4142135381698608f * erfinv_xla(u);  // float32(sqrt(2))
}

// ---------------------------------------------------------------------------
// Kernel A: fused normalize + perturbed top-k.  One wave per (b, sample) row;
// 4 waves/block; 1000 blocks.  Norm recomputed in-register per wave
// (bit-identical expression to the old scores_kernel).  Output: dense sorted
// index list topk_out[r][k] via plain stores (no atomics, no zeroed buffer).
// ---------------------------------------------------------------------------
__global__ __launch_bounds__(256) void topk_kernel(
    const float* __restrict__ scores, int* __restrict__ topk_out) {
    const int wid = threadIdx.x >> 6;
    const int lane = threadIdx.x & 63;
    const int r = blockIdx.x * 4 + wid;  // 0..3999  (= b*500 + n)
    const int b = r / NSAMP;

    const float s0 = scores[b * DIM + lane];
    const float s1 = scores[b * DIM + 64 + lane];
    const float s2 = scores[b * DIM + 128 + lane];
    const float s3 = scores[b * DIM + 192 + lane];
    float mx = fmaxf(fmaxf(s0, s1), fmaxf(s2, s3));
    float mn = fminf(fminf(s0, s1), fminf(s2, s3));
#pragma unroll
    for (int off = 1; off < 64; off <<= 1) {
        mx = fmaxf(mx, __shfl_xor(mx, off, 64));
        mn = fminf(mn, __shfl_xor(mn, off, 64));
    }
    const float den = mx - mn + 1e-5f;

    const uint32_t base = (uint32_t)r * 256u;
    float v0 = (s0 - mn) / den + jax_normal_at(base + (uint32_t)lane)        * 0.05f;
    float v1 = (s1 - mn) / den + jax_normal_at(base + 64u + (uint32_t)lane)  * 0.05f;
    float v2 = (s2 - mn) / den + jax_normal_at(base + 128u + (uint32_t)lane) * 0.05f;
    float v3 = (s3 - mn) / den + jax_normal_at(base + 192u + (uint32_t)lane) * 0.05f;

    int chosen[K_TOP];
#pragma unroll
    for (int it = 0; it < K_TOP; ++it) {
        float bv = v0; int bd = lane;
        { int d = 64 + lane;  if (v1 > bv || (v1 == bv && d < bd)) { bv = v1; bd = d; } }
        { int d = 128 + lane; if (v2 > bv || (v2 == bv && d < bd)) { bv = v2; bd = d; } }
        { int d = 192 + lane; if (v3 > bv || (v3 == bv && d < bd)) { bv = v3; bd = d; } }
#pragma unroll
        for (int off = 1; off < 64; off <<= 1) {
            float ov = __shfl_xor(bv, off, 64);
            int   od = __shfl_xor(bd, off, 64);
            if (ov > bv || (ov == bv && od < bd)) { bv = ov; bd = od; }
        }
        chosen[it] = bd;
        if ((bd & 63) == lane) {
            int q = bd >> 6;
            if (q == 0) v0 = -__builtin_inff();
            else if (q == 1) v1 = -__builtin_inff();
            else if (q == 2) v2 = -__builtin_inff();
            else v3 = -__builtin_inff();
        }
    }
    // sort 10 indices ascending (identical in every lane; static network)
#pragma unroll
    for (int a = 0; a < K_TOP - 1; ++a)
#pragma unroll
        for (int t = 0; t < K_TOP - 1 - a; ++t) {
            int x0 = chosen[t], x1 = chosen[t + 1];
            chosen[t] = min(x0, x1);
            chosen[t + 1] = max(x0, x1);
        }
    if (lane == 0) {
        int* row = topk_out + r * K_TOP;
#pragma unroll
        for (int k = 0; k < K_TOP; ++k) row[k] = chosen[k];
    }
}

// ---------------------------------------------------------------------------
// 10-way FMA of one float4 against the 10 window weights (LDS, padded to 12).
// ---------------------------------------------------------------------------
__device__ __forceinline__ void fma10(float4 acc[K_TOP], const float4 v,
                                      const float* __restrict__ w12) {
    const float4 wA = *(const float4*)(w12);
    const float4 wB = *(const float4*)(w12 + 4);
    const float2 wC = *(const float2*)(w12 + 8);
    const float wk[K_TOP] = {wA.x, wA.y, wA.z, wA.w,
                             wB.x, wB.y, wB.z, wB.w, wC.x, wC.y};
#pragma unroll
    for (int k = 0; k < K_TOP; ++k) {
        acc[k].x = fmaf(wk[k], v.x, acc[k].x);
        acc[k].y = fmaf(wk[k], v.y, acc[k].y);
        acc[k].z = fmaf(wk[k], v.z, acc[k].z);
        acc[k].w = fmaf(wk[k], v.w, acc[k].w);
    }
}

// ---------------------------------------------------------------------------
// Kernel B: compact + gather + (block 1536) entropy.  Blocks 0..1535:
// per-block LDS histogram of topk_out -> union windows + weights -> paired
// gather loop -> LDS tree combine.  All staging aliased onto the 20KB tree
// buffer (phases separated by barriers).  grid = 1537 x 256.
// ---------------------------------------------------------------------------
__global__ __launch_bounds__(256) void gather_kernel(
    const float* __restrict__ x, const float* __restrict__ scores,
    const int* __restrict__ topk_out, float* __restrict__ out) {
    __shared__ float4 ldsbuf[2][K_TOP][64];  // 20480 B
    __shared__ int wsum[4];
    __shared__ float s_ent[BATCH];
    int*   hist = (int*)&ldsbuf[0][0][0];    // [K_TOP*DIM] = 10240 B
    int*   s_ij = (int*)&ldsbuf[0][0][0];    // [256]   (sequenced reuse)
    float* s_wt = (float*)(s_ij + DIM);      // [256*WSTRIDE]

    const int tid = threadIdx.x;
    const int wid = tid >> 6, lane = tid & 63;

    if (blockIdx.x == BATCH * 3 * 64) {
        // entropy block: identical math to the old scores_kernel.
#pragma unroll
        for (int bb = 0; bb < 2; ++bb) {
            const int b = wid * 2 + bb;
            const float s0 = scores[b * DIM + lane];
            const float s1 = scores[b * DIM + 64 + lane];
            const float s2 = scores[b * DIM + 128 + lane];
            const float s3 = scores[b * DIM + 192 + lane];
            float mx = fmaxf(fmaxf(s0, s1), fmaxf(s2, s3));
#pragma unroll
            for (int off = 1; off < 64; off <<= 1)
                mx = fmaxf(mx, __shfl_xor(mx, off, 64));
            const float e0 = expf(s0 - mx), e1 = expf(s1 - mx);
            const float e2 = expf(s2 - mx), e3 = expf(s3 - mx);
            float se = e0 + e1 + e2 + e3;
#pragma unroll
            for (int off = 1; off < 64; off <<= 1) se += __shfl_xor(se, off, 64);
            const float lse = logf(se);
            float pl = e0 * ((s0 - mx) - lse) + e1 * ((s1 - mx) - lse) +
                       e2 * ((s2 - mx) - lse) + e3 * ((s3 - mx) - lse);
#pragma unroll
            for (int off = 1; off < 64; off <<= 1) pl += __shfl_xor(pl, off, 64);
            if (lane == 0) s_ent[b] = -(pl / se);
        }
        __syncthreads();
        if (tid == 0) {
            float acc = 0.f;
#pragma unroll
            for (int b = 0; b < BATCH; ++b) acc += s_ent[b];
            out[PATCHES_ELEMS] = acc * 0.125f;  // mean over 8 (exact /8)
        }
        return;
    }

    const int blk = blockIdx.x;
    const int rc = blk & 63;        // rows h = rc*2, rc*2+1
    const int bc = blk >> 6;        // b*3 + c
    const int b = bc / 3;
    const int c = bc % 3;
    const int h = (rc << 1) + (lane >> 5);
    const int w0 = (lane & 31) << 2;
    const float* img = x + (size_t)bc * (1024 * 1024);

    // --- phase 1: histogram counts[k][d] from this batch's topk rows ---
    for (int i = tid; i < K_TOP * DIM; i += 256) hist[i] = 0;
    __syncthreads();
    const int* tk = topk_out + b * NSAMP * K_TOP;
    for (int i = tid; i < NSAMP * K_TOP; i += 256) {
        const int k = i % K_TOP;
        atomicAdd(&hist[k * DIM + tk[i]], 1);
    }
    __syncthreads();

    // --- phase 2: pull my window's counts into regs; compact via scan ---
    int cnt[K_TOP]; int any = 0;
#pragma unroll
    for (int k = 0; k < K_TOP; ++k) { cnt[k] = hist[k * DIM + tid]; any |= cnt[k]; }
    const int flag = any ? 1 : 0;
    int incl = flag;
#pragma unroll
    for (int off = 1; off < 64; off <<= 1) {
        int t = __shfl_up(incl, off, 64);
        if (lane >= off) incl += t;
    }
    if (lane == 63) wsum[wid] = incl;
    __syncthreads();  // all hist reads done; wsum visible
    int woff = 0;
#pragma unroll
    for (int w = 0; w < 4; ++w) if (w < wid) woff += wsum[w];
    const int nnz = wsum[0] + wsum[1] + wsum[2] + wsum[3];
    if (flag) {
        const int pos = woff + incl - flag;
        s_ij[pos] = tid;
#pragma unroll
        for (int k = 0; k < K_TOP; ++k)
            s_wt[pos * WSTRIDE + k] = (float)cnt[k] / 500.0f;
    }
    __syncthreads();

    // --- phase 3: paired gather loop (same as R13) ---
    float4 acc[K_TOP];
#pragma unroll
    for (int k = 0; k < K_TOP; ++k) acc[k] = make_float4(0.f, 0.f, 0.f, 0.f);

    for (int t0 = wid * 2; t0 < nnz; t0 += 8) {
        const int t1 = t0 + 1;          // wave-uniform validity
        const int ij0 = s_ij[t0];
        const int y0  = (ij0 >> 4) * 64 + h - 32;
        const int xc0 = (ij0 & 15) * 64 + w0 - 32;
        float4 v0 = make_float4(0.f, 0.f, 0.f, 0.f);
        if ((unsigned)y0 < 1024u && (unsigned)xc0 < 1024u)
            v0 = *(const float4*)(img + ((size_t)y0 << 10) + xc0);

        if (t1 < nnz) {
            const int ij1 = s_ij[t1];
            const int y1  = (ij1 >> 4) * 64 + h - 32;
            const int xc1 = (ij1 & 15) * 64 + w0 - 32;
            float4 v1 = make_float4(0.f, 0.f, 0.f, 0.f);
            if ((unsigned)y1 < 1024u && (unsigned)xc1 < 1024u)
                v1 = *(const float4*)(img + ((size_t)y1 << 10) + xc1);
            fma10(acc, v0, &s_wt[t0 * WSTRIDE]);
            fma10(acc, v1, &s_wt[t1 * WSTRIDE]);
        } else {
            fma10(acc, v0, &s_wt[t0 * WSTRIDE]);
        }
    }

    // --- phase 4: tree combine (barrier-sequenced ldsbuf reuse) ---
    __syncthreads();
    if (wid >= 2) {
#pragma unroll
        for (int k = 0; k < K_TOP; ++k) ldsbuf[wid - 2][k][lane] = acc[k];
    }
    __syncthreads();
    if (wid < 2) {
#pragma unroll
        for (int k = 0; k < K_TOP; ++k) {
            const float4 t = ldsbuf[wid][k][lane];
            acc[k].x += t.x; acc[k].y += t.y; acc[k].z += t.z; acc[k].w += t.w;
        }
    }
    __syncthreads();
    if (wid == 1) {
#pragma unroll
        for (int k = 0; k < K_TOP; ++k) ldsbuf[0][k][lane] = acc[k];
    }
    __syncthreads();
    if (wid == 0) {
#pragma unroll
        for (int k = 0; k < K_TOP; ++k) {
            const float4 t = ldsbuf[0][k][lane];
            acc[k].x += t.x; acc[k].y += t.y; acc[k].z += t.z; acc[k].w += t.w;
            const size_t oidx =
                (((size_t)((b * K_TOP + k) * 3 + c)) << 14) + (h << 7) + w0;
            *(float4*)(out + oidx) = acc[k];
        }
    }
}

// ---------------------------------------------------------------------------
extern "C" void kernel_launch(void* const* d_in, const int* in_sizes, int n_in,
                              void* d_out, int out_size, void* d_ws,
                              size_t ws_size, hipStream_t stream) {
    const float* x_high = (const float*)d_in[0];   // (8,3,1024,1024) f32
    const float* scores = (const float*)d_in[1];   // (8,16,16) f32
    float* out = (float*)d_out;                    // 3,932,160 patches + 1 entr

    int* topk_out = (int*)d_ws;                    // 4000 x 10 ints

    topk_kernel<<<1000, 256, 0, stream>>>(scores, topk_out);
    gather_kernel<<<BATCH * 3 * 64 + 1, 256, 0, stream>>>(x_high, scores,
                                                          topk_out, out);
}